// Round 7
// baseline (975.825 us; speedup 1.0000x reference)
//
#include <hip/hip_runtime.h>
#include <hip/hip_bf16.h>

#define N_NODES 50000
#define IN_C    96
#define HID_C   128
#define OUT_C   64
#define MROWS   50016 // 32-row-tile padded M

// CSR-build partition params
#define NB      400   // coarse buckets
#define BSZ     125   // nodes per bucket (400*125 = 50000); local dst fits 8 bits
#define WCHUNK  4096  // edges per workgroup in partition passes
#define NWG     196   // ceil(800000/4096)

typedef __attribute__((ext_vector_type(8))) short short8;  // 8 bf16 (4 VGPR)
typedef __attribute__((ext_vector_type(4))) float f32x4;

// round-to-nearest-even fp32 -> bf16 bits
__device__ inline unsigned int f2bf(float f) {
    unsigned int u = __float_as_uint(f);
    return (u + 0x7fffu + ((u >> 16) & 1u)) >> 16;
}
__device__ inline unsigned int pack2(float lo, float hi) {
    return f2bf(lo) | (f2bf(hi) << 16);
}
__device__ inline float blo(unsigned int u) { return __uint_as_float(u << 16); }
__device__ inline float bhi(unsigned int u) { return __uint_as_float(u & 0xffff0000u); }

// ---------------------------------------------------------------------------
// P1: per-WG coarse histogram over 400 buckets (LDS, no global atomics).
// ---------------------------------------------------------------------------
__global__ __launch_bounds__(256) void parta_hist(
    const int* __restrict__ dst, int* __restrict__ gh, int E)
{
    __shared__ int h[NB];
    int t = threadIdx.x;
    for (int i = t; i < NB; i += 256) h[i] = 0;
    __syncthreads();
    int base_e = blockIdx.x * WCHUNK;
    for (int i = t; i < WCHUNK; i += 256) {
        int e = base_e + i;
        if (e < E) atomicAdd(&h[dst[e] / BSZ], 1);
    }
    __syncthreads();
    for (int i = t; i < NB; i += 256) gh[blockIdx.x * NB + i] = h[i];
}

// ---------------------------------------------------------------------------
// P2: bucket bases (exclusive scan of totals) + per-(WG,bucket) offsets.
// 512 threads so thread t owns bucket t (NB=400).
// ---------------------------------------------------------------------------
__global__ __launch_bounds__(512) void parta_scan(
    const int* __restrict__ gh, int* __restrict__ ofs,
    int* __restrict__ base)
{
    __shared__ int buf[512];
    int t = threadIdx.x;
    int tot = 0;
    if (t < NB) {
        for (int w = 0; w < NWG; w++) tot += gh[w * NB + t];
    }
    buf[t] = tot;
    __syncthreads();
    for (int off = 1; off < 512; off <<= 1) {       // inclusive scan
        int v = (t >= off) ? buf[t - off] : 0;
        __syncthreads();
        buf[t] += v;
        __syncthreads();
    }
    if (t < NB) {
        int excl = buf[t] - tot;
        base[t] = excl;
        if (t == NB - 1) base[NB] = excl + tot;     // == E
        int run = excl;
        for (int w = 0; w < NWG; w++) {
            ofs[w * NB + t] = run;
            run += gh[w * NB + t];
        }
    }
}

// ---------------------------------------------------------------------------
// P3: partition edges into bucket-ordered packed records:
// rec = src (16b) | bucket-local dst (8b) << 16.  4 B/edge, coalesced runs.
// ---------------------------------------------------------------------------
__global__ __launch_bounds__(256) void parta_scatter(
    const int* __restrict__ src, const int* __restrict__ dst,
    const int* __restrict__ ofs, unsigned int* __restrict__ pairs, int E)
{
    __shared__ int cur[NB];
    int t = threadIdx.x;
    for (int i = t; i < NB; i += 256) cur[i] = ofs[blockIdx.x * NB + i];
    __syncthreads();
    int base_e = blockIdx.x * WCHUNK;
    for (int i = t; i < WCHUNK; i += 256) {
        int e = base_e + i;
        if (e < E) {
            int d = dst[e];
            int b = d / BSZ;
            int pos = atomicAdd(&cur[b], 1);
            pairs[pos] = (unsigned)src[e] | ((unsigned)(d - b * BSZ) << 16);
        }
    }
}

// ---------------------------------------------------------------------------
// Converter: x fp32 -> xb bf16 (row layout [50000][96]).
// ---------------------------------------------------------------------------
__global__ __launch_bounds__(256) void conv_x_kernel(
    const float* __restrict__ x, uint4* __restrict__ xb4)
{
    int idx = blockIdx.x * 256 + threadIdx.x;     // N*12
    if (idx >= N_NODES * 12) return;
    const float4* x4 = (const float4*)x;
    float4 u = x4[(size_t)idx * 2];
    float4 v = x4[(size_t)idx * 2 + 1];
    uint4 w;
    w.x = pack2(u.x, u.y); w.y = pack2(u.z, u.w);
    w.z = pack2(v.x, v.y); w.w = pack2(v.z, v.w);
    xb4[idx] = w;
}

// Fused weight convert: W1t[128][192] and W2t[128][128].
__global__ __launch_bounds__(256) void conv_w_kernel(
    const float* __restrict__ w1l, const float* __restrict__ w1r,
    const float* __restrict__ w2l, const float* __restrict__ w2r,
    unsigned short* __restrict__ wt1, unsigned short* __restrict__ wt2)
{
    int i = blockIdx.x * 256 + threadIdx.x;
    if (i < 128 * 192) {
        int col = i / 192, k = i - col * 192;
        float v = (k < 96) ? w1l[k * 128 + col] : w1r[(k - 96) * 128 + col];
        wt1[i] = (unsigned short)f2bf(v);
    } else {
        int j = i - 128 * 192;
        if (j < 128 * 128) {
            int col = j / 128, k = j - col * 128;
            float v = (col < 64) ? w2l[k * 64 + col] : w2r[k * 64 + col - 64];
            wt2[j] = (unsigned short)f2bf(v);
        }
    }
}

// ---------------------------------------------------------------------------
// Gather 1 (bucket-LDS): WG = (bucket, 48-ch half). Streams the bucket's
// packed edge records; fp32 LDS accumulation via ds_add (fire-and-forget,
// no loop-carried latency chain, zero divergence). Flush: /deg, bf16 pack.
// ---------------------------------------------------------------------------
__global__ __launch_bounds__(256) void gather1_bucket(
    const unsigned int* __restrict__ pairs, const int* __restrict__ base,
    const uint4* __restrict__ xb4, uint4* __restrict__ agg4)
{
    constexpr int STR = 49;                       // 48 ch + 1 pad (odd stride)
    __shared__ float acc[BSZ * STR];              // 24500 B
    __shared__ int ldeg[BSZ];
    int wg = blockIdx.x;
    int b = wg >> 1, hf = wg & 1;
    int t = threadIdx.x;
    for (int i = t; i < BSZ * STR; i += 256) acc[i] = 0.f;
    for (int i = t; i < BSZ; i += 256) ldeg[i] = 0;
    __syncthreads();
    int beg = base[b], end = base[b + 1];
    for (int i = beg + t; i < end; i += 256) {
        unsigned int pr = pairs[i];
        int s  = (int)(pr & 0xffffu);
        int ld = (int)(pr >> 16);
        atomicAdd(&ldeg[ld], 1);
        const uint4* row = xb4 + (size_t)s * 12 + hf * 6;
        float* d = acc + ld * STR;
#pragma unroll
        for (int c = 0; c < 6; c++) {
            uint4 v = row[c];
            unsafeAtomicAdd(d + c * 8 + 0, blo(v.x));
            unsafeAtomicAdd(d + c * 8 + 1, bhi(v.x));
            unsafeAtomicAdd(d + c * 8 + 2, blo(v.y));
            unsafeAtomicAdd(d + c * 8 + 3, bhi(v.y));
            unsafeAtomicAdd(d + c * 8 + 4, blo(v.z));
            unsafeAtomicAdd(d + c * 8 + 5, bhi(v.z));
            unsafeAtomicAdd(d + c * 8 + 6, blo(v.w));
            unsafeAtomicAdd(d + c * 8 + 7, bhi(v.w));
        }
    }
    __syncthreads();
    int node0 = b * BSZ;
    for (int i = t; i < BSZ * 6; i += 256) {
        int n = i / 6, c = i - n * 6;
        float id = 1.0f / (float)max(ldeg[n], 1);
        const float* s = acc + n * STR + c * 8;
        uint4 w;
        w.x = pack2(s[0] * id, s[1] * id);
        w.y = pack2(s[2] * id, s[3] * id);
        w.z = pack2(s[4] * id, s[5] * id);
        w.w = pack2(s[6] * id, s[7] * id);
        agg4[(size_t)(node0 + n) * 12 + hf * 6 + c] = w;
    }
}

// ---------------------------------------------------------------------------
// GEMM1 (bf16 MFMA, persistent-W): h = relu([agg|x] @ W1t^T + b1), h bf16.
// A-tile k-cols 0..95 from agg, 96..191 from xb (saves a 9.6 MB A1 copy).
// ---------------------------------------------------------------------------
#define NT1 (MROWS / 32)
__global__ __launch_bounds__(256) void gemm1_mfma(
    const uint4* __restrict__ agg4, const uint4* __restrict__ xb4,
    const uint4* __restrict__ w4,
    const float* __restrict__ b1, unsigned short* __restrict__ h)
{
    constexpr int KD = 192, KP = KD + 8;          // padded bf16 stride (200)
    __shared__ unsigned short lw[128 * KP];       // 51200 B
    __shared__ unsigned short la[32 * KP];        // 12800 B
    int t = threadIdx.x;
    uint4* lw4 = (uint4*)lw;
    uint4* la4 = (uint4*)la;
    for (int i = t; i < 128 * 24; i += 256) {
        int r = i / 24, c = i - r * 24;
        lw4[r * 25 + c] = w4[i];
    }
    int wave = t >> 6, lane = t & 63;
    int m = lane & 15, half = lane >> 4;          // 0..3
    int koff = half * 8;
    int col0 = wave * 32 + m;
    int col1 = wave * 32 + 16 + m;
    float bias0 = b1[col0], bias1 = b1[col1];

    for (int tile = blockIdx.x; tile < NT1; tile += 512) {
        int row0 = tile * 32;
        __syncthreads();                           // prev readers done; lw ready
        for (int i = t; i < 32 * 24; i += 256) {
            int r = i / 24, c = i - r * 24;
            // rows >= N_NODES read garbage (valid memory) - discarded at write
            la4[r * 25 + c] = (c < 12)
                ? agg4[(size_t)(row0 + r) * 12 + c]
                : xb4[(size_t)(row0 + r) * 12 + (c - 12)];
        }
        __syncthreads();

        f32x4 acc00 = {}, acc01 = {}, acc10 = {}, acc11 = {};
#pragma unroll
        for (int k0 = 0; k0 < KD; k0 += 32) {
            short8 A0 = *(const short8*)&la[(m)      * KP + k0 + koff];
            short8 A1 = *(const short8*)&la[(16 + m) * KP + k0 + koff];
            short8 B0 = *(const short8*)&lw[(wave * 32 + m)      * KP + k0 + koff];
            short8 B1 = *(const short8*)&lw[(wave * 32 + 16 + m) * KP + k0 + koff];
            acc00 = __builtin_amdgcn_mfma_f32_16x16x32_bf16(A0, B0, acc00, 0, 0, 0);
            acc01 = __builtin_amdgcn_mfma_f32_16x16x32_bf16(A0, B1, acc01, 0, 0, 0);
            acc10 = __builtin_amdgcn_mfma_f32_16x16x32_bf16(A1, B0, acc10, 0, 0, 0);
            acc11 = __builtin_amdgcn_mfma_f32_16x16x32_bf16(A1, B1, acc11, 0, 0, 0);
        }
#pragma unroll
        for (int reg = 0; reg < 4; reg++) {
            int r0 = row0 + half * 4 + reg;
            int r1 = r0 + 16;
            if (r0 < N_NODES) {
                h[(size_t)r0 * 128 + col0] = (unsigned short)f2bf(fmaxf(acc00[reg] + bias0, 0.f));
                h[(size_t)r0 * 128 + col1] = (unsigned short)f2bf(fmaxf(acc01[reg] + bias1, 0.f));
            }
            if (r1 < N_NODES) {
                h[(size_t)r1 * 128 + col0] = (unsigned short)f2bf(fmaxf(acc10[reg] + bias0, 0.f));
                h[(size_t)r1 * 128 + col1] = (unsigned short)f2bf(fmaxf(acc11[reg] + bias1, 0.f));
            }
        }
    }
}

// ---------------------------------------------------------------------------
// GEMM2 (bf16 MFMA, persistent-W): [p|q] = h @ W2t^T; p bf16 (cols 0..63),
// q = +b2 -> out fp32 (cols 64..127).
// ---------------------------------------------------------------------------
__global__ __launch_bounds__(256) void gemm2_mfma(
    const uint4* __restrict__ h4, const uint4* __restrict__ w4,
    const float* __restrict__ b2, unsigned short* __restrict__ p,
    float* __restrict__ out)
{
    constexpr int KD = 128, KP = KD + 8;          // 136
    __shared__ unsigned short lw[128 * KP];       // 34816 B
    __shared__ unsigned short la[32 * KP];        // 8704 B
    int t = threadIdx.x;
    uint4* lw4 = (uint4*)lw;
    uint4* la4 = (uint4*)la;
    for (int i = t; i < 128 * 16; i += 256) {
        int r = i >> 4, c = i & 15;
        lw4[r * 17 + c] = w4[i];
    }
    int wave = t >> 6, lane = t & 63;
    int m = lane & 15, half = lane >> 4;
    int koff = half * 8;
    int col0 = wave * 32 + m;
    int col1 = wave * 32 + 16 + m;

    for (int tile = blockIdx.x; tile < NT1; tile += 512) {
        int row0 = tile * 32;
        __syncthreads();
        for (int i = t; i < 32 * 16; i += 256) {
            int r = i >> 4, c = i & 15;
            la4[r * 17 + c] = h4[(size_t)(row0 + r) * 16 + c];
        }
        __syncthreads();

        f32x4 acc00 = {}, acc01 = {}, acc10 = {}, acc11 = {};
#pragma unroll
        for (int k0 = 0; k0 < KD; k0 += 32) {
            short8 A0 = *(const short8*)&la[(m)      * KP + k0 + koff];
            short8 A1 = *(const short8*)&la[(16 + m) * KP + k0 + koff];
            short8 B0 = *(const short8*)&lw[(wave * 32 + m)      * KP + k0 + koff];
            short8 B1 = *(const short8*)&lw[(wave * 32 + 16 + m) * KP + k0 + koff];
            acc00 = __builtin_amdgcn_mfma_f32_16x16x32_bf16(A0, B0, acc00, 0, 0, 0);
            acc01 = __builtin_amdgcn_mfma_f32_16x16x32_bf16(A0, B1, acc01, 0, 0, 0);
            acc10 = __builtin_amdgcn_mfma_f32_16x16x32_bf16(A1, B0, acc10, 0, 0, 0);
            acc11 = __builtin_amdgcn_mfma_f32_16x16x32_bf16(A1, B1, acc11, 0, 0, 0);
        }
#pragma unroll
        for (int reg = 0; reg < 4; reg++) {
            int r0 = row0 + half * 4 + reg;
            int r1 = r0 + 16;
            float v00 = acc00[reg], v01 = acc01[reg];
            float v10 = acc10[reg], v11 = acc11[reg];
            if (r0 < N_NODES) {
                if (col0 < 64) p[(size_t)r0 * 64 + col0] = (unsigned short)f2bf(v00);
                else           out[(size_t)r0 * 64 + col0 - 64] = v00 + b2[col0 - 64];
                if (col1 < 64) p[(size_t)r0 * 64 + col1] = (unsigned short)f2bf(v01);
                else           out[(size_t)r0 * 64 + col1 - 64] = v01 + b2[col1 - 64];
            }
            if (r1 < N_NODES) {
                if (col0 < 64) p[(size_t)r1 * 64 + col0] = (unsigned short)f2bf(v10);
                else           out[(size_t)r1 * 64 + col0 - 64] = v10 + b2[col0 - 64];
                if (col1 < 64) p[(size_t)r1 * 64 + col1] = (unsigned short)f2bf(v11);
                else           out[(size_t)r1 * 64 + col1 - 64] = v11 + b2[col1 - 64];
            }
        }
    }
}

// ---------------------------------------------------------------------------
// Gather 2 (bucket-LDS) + finalize: out[n] += (sum p[j]) / deg(n).
// WG = (bucket, 32-ch half).
// ---------------------------------------------------------------------------
__global__ __launch_bounds__(256) void gather2_bucket(
    const unsigned int* __restrict__ pairs, const int* __restrict__ base,
    const uint4* __restrict__ p4, float* __restrict__ out)
{
    constexpr int STR = 33;                       // 32 ch + 1 pad
    __shared__ float acc[BSZ * STR];              // 16500 B
    __shared__ int ldeg[BSZ];
    int wg = blockIdx.x;
    int b = wg >> 1, hf = wg & 1;
    int t = threadIdx.x;
    for (int i = t; i < BSZ * STR; i += 256) acc[i] = 0.f;
    for (int i = t; i < BSZ; i += 256) ldeg[i] = 0;
    __syncthreads();
    int beg = base[b], end = base[b + 1];
    for (int i = beg + t; i < end; i += 256) {
        unsigned int pr = pairs[i];
        int s  = (int)(pr & 0xffffu);
        int ld = (int)(pr >> 16);
        atomicAdd(&ldeg[ld], 1);
        const uint4* row = p4 + (size_t)s * 8 + hf * 4;
        float* d = acc + ld * STR;
#pragma unroll
        for (int c = 0; c < 4; c++) {
            uint4 v = row[c];
            unsafeAtomicAdd(d + c * 8 + 0, blo(v.x));
            unsafeAtomicAdd(d + c * 8 + 1, bhi(v.x));
            unsafeAtomicAdd(d + c * 8 + 2, blo(v.y));
            unsafeAtomicAdd(d + c * 8 + 3, bhi(v.y));
            unsafeAtomicAdd(d + c * 8 + 4, blo(v.z));
            unsafeAtomicAdd(d + c * 8 + 5, bhi(v.z));
            unsafeAtomicAdd(d + c * 8 + 6, blo(v.w));
            unsafeAtomicAdd(d + c * 8 + 7, bhi(v.w));
        }
    }
    __syncthreads();
    int node0 = b * BSZ;
    float4* o4 = (float4*)out;
    for (int i = t; i < BSZ * 8; i += 256) {
        int n = i >> 3, c = i & 7;
        float id = 1.0f / (float)max(ldeg[n], 1);
        const float* s = acc + n * STR + c * 4;
        size_t oi = (size_t)(node0 + n) * 16 + hf * 8 + c;
        float4 o = o4[oi];
        o.x = fmaf(s[0], id, o.x);
        o.y = fmaf(s[1], id, o.y);
        o.z = fmaf(s[2], id, o.z);
        o.w = fmaf(s[3], id, o.w);
        o4[oi] = o;
    }
}

extern "C" void kernel_launch(void* const* d_in, const int* in_sizes, int n_in,
                              void* d_out, int out_size, void* d_ws, size_t ws_size,
                              hipStream_t stream)
{
    const float* x   = (const float*)d_in[0];
    const int*   ei  = (const int*)d_in[1];
    const float* w1l = (const float*)d_in[2];
    const float* w1r = (const float*)d_in[3];
    const float* b1  = (const float*)d_in[4];
    const float* w2l = (const float*)d_in[5];
    const float* w2r = (const float*)d_in[6];
    const float* b2  = (const float*)d_in[7];
    float* out = (float*)d_out;

    int E = in_sizes[1] / 2;                  // edge_index is [2, E]
    const int* src = ei;
    const int* dst = ei + E;

    // Workspace layout (4B units, arrays kept 16B-aligned).
    int* gh   = (int*)d_ws;                            // 196*400 = 78400
    int* ofs  = gh + NWG * NB;                         // 78400
    int* base = ofs + NWG * NB;                        // 512 (NB+1 used)
    unsigned int* pairs = (unsigned int*)(base + 512); // 800000 uint
    unsigned short* xb  = (unsigned short*)(pairs + 800000); // 50000*96 bf16
    unsigned short* agg = xb + (size_t)N_NODES * IN_C; // 50016*96 bf16 (after xb: OOB tile reads land here)
    unsigned short* h   = agg + (size_t)MROWS * 96;    // 50016*128 bf16
    unsigned short* p   = h  + (size_t)MROWS * 128;    // 50000*64 bf16
    unsigned short* Wt1 = p  + (size_t)N_NODES * 64;   // 128*192 bf16
    unsigned short* Wt2 = Wt1 + 128 * 192;             // 128*128 bf16

    // Edge partition (bucket-sorted packed records; no fine CSR needed)
    parta_hist<<<NWG, 256, 0, stream>>>(dst, gh, E);
    parta_scan<<<1, 512, 0, stream>>>(gh, ofs, base);
    parta_scatter<<<NWG, 256, 0, stream>>>(src, dst, ofs, pairs, E);

    conv_x_kernel<<<(N_NODES * 12 + 255) / 256, 256, 0, stream>>>(
        x, (uint4*)xb);
    conv_w_kernel<<<(128 * 192 + 128 * 128 + 255) / 256, 256, 0, stream>>>(
        w1l, w1r, w2l, w2r, Wt1, Wt2);

    gather1_bucket<<<NB * 2, 256, 0, stream>>>(
        pairs, base, (const uint4*)xb, (uint4*)agg);

    gemm1_mfma<<<512, 256, 0, stream>>>(
        (const uint4*)agg, (const uint4*)xb, (const uint4*)Wt1, b1, h);
    gemm2_mfma<<<512, 256, 0, stream>>>(
        (const uint4*)h, (const uint4*)Wt2, b2, p, out);

    gather2_bucket<<<NB * 2, 256, 0, stream>>>(
        pairs, base, (const uint4*)p, out);
}

// Round 8
// 208.323 us; speedup vs baseline: 4.6842x; 4.6842x over previous
//
#include <hip/hip_runtime.h>
#include <hip/hip_bf16.h>

#define N_NODES 50000
#define IN_C    96
#define HID_C   128
#define OUT_C   64
#define MROWS   50016 // 32-row-tile padded M

// CSR-build partition params (R4-proven)
#define NB      200   // coarse buckets
#define BSZ     250   // nodes per bucket (200*250 = 50000)
#define WCHUNK  4096  // edges per workgroup in partition passes
#define NWG     196   // ceil(800000/4096)

typedef __attribute__((ext_vector_type(8))) short short8;  // 8 bf16 (4 VGPR)
typedef __attribute__((ext_vector_type(4))) float f32x4;

// round-to-nearest-even fp32 -> bf16 bits
__device__ inline unsigned int f2bf(float f) {
    unsigned int u = __float_as_uint(f);
    return (u + 0x7fffu + ((u >> 16) & 1u)) >> 16;
}
__device__ inline unsigned int pack2(float lo, float hi) {
    return f2bf(lo) | (f2bf(hi) << 16);
}
__device__ inline float blo(unsigned int u) { return __uint_as_float(u << 16); }
__device__ inline float bhi(unsigned int u) { return __uint_as_float(u & 0xffff0000u); }

// ---------------------------------------------------------------------------
// P1: per-WG coarse histogram (LDS, no global atomics).
// ---------------------------------------------------------------------------
__global__ __launch_bounds__(256) void parta_hist(
    const int* __restrict__ dst, int* __restrict__ gh, int E)
{
    __shared__ int h[NB];
    int t = threadIdx.x;
    if (t < NB) h[t] = 0;
    __syncthreads();
    int base_e = blockIdx.x * WCHUNK;
    for (int i = t; i < WCHUNK; i += 256) {
        int e = base_e + i;
        if (e < E) atomicAdd(&h[dst[e] / BSZ], 1);
    }
    __syncthreads();
    if (t < NB) gh[blockIdx.x * NB + t] = h[t];
}

// ---------------------------------------------------------------------------
// P2: bucket bases (exclusive scan of totals) + per-(WG,bucket) offsets.
// ---------------------------------------------------------------------------
__global__ __launch_bounds__(256) void parta_scan(
    const int* __restrict__ gh, int* __restrict__ ofs,
    int* __restrict__ base)
{
    __shared__ int buf[256];
    int t = threadIdx.x;
    int tot = 0;
    if (t < NB) {
        for (int w = 0; w < NWG; w++) tot += gh[w * NB + t];
    }
    buf[t] = tot;
    __syncthreads();
    for (int off = 1; off < 256; off <<= 1) {       // inclusive scan
        int v = (t >= off) ? buf[t - off] : 0;
        __syncthreads();
        buf[t] += v;
        __syncthreads();
    }
    if (t < NB) {
        int excl = buf[t] - tot;
        base[t] = excl;
        if (t == NB - 1) base[NB] = excl + tot;     // == E
        int run = excl;
        for (int w = 0; w < NWG; w++) {
            ofs[w * NB + t] = run;
            run += gh[w * NB + t];
        }
    }
}

// ---------------------------------------------------------------------------
// P3: partition edges into bucket-ordered (src,dst) pairs; each WG's writes
// per bucket form a contiguous run (fully-dirty lines, no writeback ampl.).
// ---------------------------------------------------------------------------
__global__ __launch_bounds__(256) void parta_scatter(
    const int* __restrict__ src, const int* __restrict__ dst,
    const int* __restrict__ ofs, uint2* __restrict__ pairs, int E)
{
    __shared__ int cur[NB];
    int t = threadIdx.x;
    if (t < NB) cur[t] = ofs[blockIdx.x * NB + t];
    __syncthreads();
    int base_e = blockIdx.x * WCHUNK;
    for (int i = t; i < WCHUNK; i += 256) {
        int e = base_e + i;
        if (e < E) {
            int d = dst[e];
            int pos = atomicAdd(&cur[d / BSZ], 1);
            pairs[pos] = make_uint2((unsigned)src[e], (unsigned)d);
        }
    }
}

// ---------------------------------------------------------------------------
// P4: per-bucket fine CSR: LDS 250-bin histogram + scan + rank; writes
// rowstart/cnt and a contiguous adj region per bucket.
// ---------------------------------------------------------------------------
__global__ __launch_bounds__(256) void partb_csr(
    const uint2* __restrict__ pairs, const int* __restrict__ base,
    int* __restrict__ rowstart, int* __restrict__ cnt,
    int* __restrict__ adj)
{
    __shared__ int h[256];
    __shared__ int buf[256];
    __shared__ int cur[256];
    int b = blockIdx.x;
    int t = threadIdx.x;
    int beg = base[b], end = base[b + 1];
    int node0 = b * BSZ;
    h[t] = 0;
    __syncthreads();
    for (int i = beg + t; i < end; i += 256)
        atomicAdd(&h[(int)pairs[i].y - node0], 1);
    __syncthreads();
    int c = h[t];
    buf[t] = c;
    __syncthreads();
    for (int off = 1; off < 256; off <<= 1) {       // inclusive scan
        int v = (t >= off) ? buf[t - off] : 0;
        __syncthreads();
        buf[t] += v;
        __syncthreads();
    }
    int excl = buf[t] - c;
    if (t < BSZ) {
        rowstart[node0 + t] = beg + excl;
        cnt[node0 + t] = c;
    }
    cur[t] = beg + excl;
    __syncthreads();
    for (int i = beg + t; i < end; i += 256) {
        uint2 pr = pairs[i];
        int pos = atomicAdd(&cur[(int)pr.y - node0], 1);
        adj[pos] = (int)pr.x;
    }
}

// ---------------------------------------------------------------------------
// Converter: x fp32 -> xb bf16 (row layout [50000][96]); xb also serves as
// the k>=96 half of GEMM1's A operand (no separate A1 copy).
// ---------------------------------------------------------------------------
__global__ __launch_bounds__(256) void conv_x_kernel(
    const float* __restrict__ x, uint4* __restrict__ xb4)
{
    int idx = blockIdx.x * 256 + threadIdx.x;     // N*12
    if (idx >= N_NODES * 12) return;
    const float4* x4 = (const float4*)x;
    float4 u = x4[(size_t)idx * 2];
    float4 v = x4[(size_t)idx * 2 + 1];
    uint4 w;
    w.x = pack2(u.x, u.y); w.y = pack2(u.z, u.w);
    w.z = pack2(v.x, v.y); w.w = pack2(v.z, v.w);
    xb4[idx] = w;
}

// Fused weight convert: W1t[128][192] and W2t[128][128].
__global__ __launch_bounds__(256) void conv_w_kernel(
    const float* __restrict__ w1l, const float* __restrict__ w1r,
    const float* __restrict__ w2l, const float* __restrict__ w2r,
    unsigned short* __restrict__ wt1, unsigned short* __restrict__ wt2)
{
    int i = blockIdx.x * 256 + threadIdx.x;
    if (i < 128 * 192) {
        int col = i / 192, k = i - col * 192;
        float v = (k < 96) ? w1l[k * 128 + col] : w1r[(k - 96) * 128 + col];
        wt1[i] = (unsigned short)f2bf(v);
    } else {
        int j = i - 128 * 192;
        if (j < 128 * 128) {
            int col = j / 128, k = j - col * 128;
            float v = (col < 64) ? w2l[k * 64 + col] : w2r[k * 64 + col - 64];
            wt2[j] = (unsigned short)f2bf(v);
        }
    }
}

// ---------------------------------------------------------------------------
// Gather 1: agg[n] = (sum_{j in N(n)} xb[j]) / deg(n), bf16 out [50000][96].
// thread = (node, 16B chunk c in 0..11); manual 2-edge unroll for MLP.
// ---------------------------------------------------------------------------
__global__ __launch_bounds__(256) void gather1_kernel(
    const int* __restrict__ rowstart, const int* __restrict__ cnt,
    const int* __restrict__ adj, const uint4* __restrict__ xb4,
    uint4* __restrict__ agg4)
{
    int idx = blockIdx.x * 256 + threadIdx.x;
    if (idx >= N_NODES * 12) return;
    int node = idx / 12;
    int c = idx - node * 12;
    int beg = rowstart[node];
    int d = cnt[node];
    int end = beg + d;
    float a0=0,a1=0,a2=0,a3=0,a4=0,a5=0,a6=0,a7=0;
    float b0=0,b1=0,b2=0,b3=0,b4=0,b5=0,b6=0,b7=0;
    int j = beg;
    for (; j + 1 < end; j += 2) {
        int s0 = adj[j];
        int s1 = adj[j + 1];
        uint4 u = xb4[(size_t)s0 * 12 + c];
        uint4 v = xb4[(size_t)s1 * 12 + c];
        a0 += blo(u.x); a1 += bhi(u.x); a2 += blo(u.y); a3 += bhi(u.y);
        a4 += blo(u.z); a5 += bhi(u.z); a6 += blo(u.w); a7 += bhi(u.w);
        b0 += blo(v.x); b1 += bhi(v.x); b2 += blo(v.y); b3 += bhi(v.y);
        b4 += blo(v.z); b5 += bhi(v.z); b6 += blo(v.w); b7 += bhi(v.w);
    }
    if (j < end) {
        int s0 = adj[j];
        uint4 u = xb4[(size_t)s0 * 12 + c];
        a0 += blo(u.x); a1 += bhi(u.x); a2 += blo(u.y); a3 += bhi(u.y);
        a4 += blo(u.z); a5 += bhi(u.z); a6 += blo(u.w); a7 += bhi(u.w);
    }
    a0 += b0; a1 += b1; a2 += b2; a3 += b3;
    a4 += b4; a5 += b5; a6 += b6; a7 += b7;
    float id = 1.0f / (float)max(d, 1);
    uint4 w;
    w.x = pack2(a0 * id, a1 * id); w.y = pack2(a2 * id, a3 * id);
    w.z = pack2(a4 * id, a5 * id); w.w = pack2(a6 * id, a7 * id);
    agg4[(size_t)node * 12 + c] = w;
}

// ---------------------------------------------------------------------------
// GEMM1 (bf16 MFMA): h = relu([agg|x] @ W1t^T + b1)  [50000 x 128], h bf16.
// A-tile k-cols 0..95 from agg, 96..191 from xb. Non-persistent (R4-proven).
// ---------------------------------------------------------------------------
__global__ __launch_bounds__(256) void gemm1_mfma(
    const uint4* __restrict__ agg4, const uint4* __restrict__ xb4,
    const uint4* __restrict__ w4,
    const float* __restrict__ b1, unsigned short* __restrict__ h)
{
    constexpr int KD = 192, KP = KD + 8;          // padded bf16 stride (200)
    __shared__ unsigned short lw[128 * KP];       // 51200 B
    __shared__ unsigned short la[32 * KP];        // 12800 B
    int t = threadIdx.x;
    uint4* lw4 = (uint4*)lw;
    uint4* la4 = (uint4*)la;
    for (int i = t; i < 128 * 24; i += 256) {
        int r = i / 24, c = i - r * 24;
        lw4[r * 25 + c] = w4[i];
    }
    int row0 = blockIdx.x * 32;
    for (int i = t; i < 32 * 24; i += 256) {
        int r = i / 24, c = i - r * 24;
        // rows >= N_NODES: xb reads run into agg region (valid mem, discarded)
        la4[r * 25 + c] = (c < 12)
            ? agg4[(size_t)(row0 + r) * 12 + c]
            : xb4[(size_t)(row0 + r) * 12 + (c - 12)];
    }
    __syncthreads();

    int wave = t >> 6, lane = t & 63;
    int m = lane & 15, half = lane >> 4;          // 0..3
    int koff = half * 8;
    f32x4 acc00 = {}, acc01 = {}, acc10 = {}, acc11 = {};
#pragma unroll
    for (int k0 = 0; k0 < KD; k0 += 32) {
        short8 A0 = *(const short8*)&la[(m)      * KP + k0 + koff];
        short8 A1 = *(const short8*)&la[(16 + m) * KP + k0 + koff];
        short8 B0 = *(const short8*)&lw[(wave * 32 + m)      * KP + k0 + koff];
        short8 B1 = *(const short8*)&lw[(wave * 32 + 16 + m) * KP + k0 + koff];
        acc00 = __builtin_amdgcn_mfma_f32_16x16x32_bf16(A0, B0, acc00, 0, 0, 0);
        acc01 = __builtin_amdgcn_mfma_f32_16x16x32_bf16(A0, B1, acc01, 0, 0, 0);
        acc10 = __builtin_amdgcn_mfma_f32_16x16x32_bf16(A1, B0, acc10, 0, 0, 0);
        acc11 = __builtin_amdgcn_mfma_f32_16x16x32_bf16(A1, B1, acc11, 0, 0, 0);
    }
    int col0 = wave * 32 + m;
    int col1 = wave * 32 + 16 + m;
    float bias0 = b1[col0], bias1 = b1[col1];
#pragma unroll
    for (int reg = 0; reg < 4; reg++) {
        int r0 = row0 + half * 4 + reg;
        int r1 = r0 + 16;
        if (r0 < N_NODES) {
            h[(size_t)r0 * 128 + col0] = (unsigned short)f2bf(fmaxf(acc00[reg] + bias0, 0.f));
            h[(size_t)r0 * 128 + col1] = (unsigned short)f2bf(fmaxf(acc01[reg] + bias1, 0.f));
        }
        if (r1 < N_NODES) {
            h[(size_t)r1 * 128 + col0] = (unsigned short)f2bf(fmaxf(acc10[reg] + bias0, 0.f));
            h[(size_t)r1 * 128 + col1] = (unsigned short)f2bf(fmaxf(acc11[reg] + bias1, 0.f));
        }
    }
}

// ---------------------------------------------------------------------------
// GEMM2 (bf16 MFMA): [p|q] = h @ W2t^T; p bf16 (cols 0..63),
// q = +b2 -> out fp32 (cols 64..127). Non-persistent (R4-proven).
// ---------------------------------------------------------------------------
__global__ __launch_bounds__(256) void gemm2_mfma(
    const uint4* __restrict__ h4, const uint4* __restrict__ w4,
    const float* __restrict__ b2, unsigned short* __restrict__ p,
    float* __restrict__ out)
{
    constexpr int KD = 128, KP = KD + 8;          // 136
    __shared__ unsigned short lw[128 * KP];       // 34816 B
    __shared__ unsigned short la[32 * KP];        // 8704 B
    int t = threadIdx.x;
    uint4* lw4 = (uint4*)lw;
    uint4* la4 = (uint4*)la;
    for (int i = t; i < 128 * 16; i += 256) {
        int r = i >> 4, c = i & 15;
        lw4[r * 17 + c] = w4[i];
    }
    int row0 = blockIdx.x * 32;
    for (int i = t; i < 32 * 16; i += 256) {
        int r = i >> 4, c = i & 15;
        la4[r * 17 + c] = h4[(size_t)(row0 + r) * 16 + c];
    }
    __syncthreads();

    int wave = t >> 6, lane = t & 63;
    int m = lane & 15, half = lane >> 4;
    int koff = half * 8;
    f32x4 acc00 = {}, acc01 = {}, acc10 = {}, acc11 = {};
#pragma unroll
    for (int k0 = 0; k0 < KD; k0 += 32) {
        short8 A0 = *(const short8*)&la[(m)      * KP + k0 + koff];
        short8 A1 = *(const short8*)&la[(16 + m) * KP + k0 + koff];
        short8 B0 = *(const short8*)&lw[(wave * 32 + m)      * KP + k0 + koff];
        short8 B1 = *(const short8*)&lw[(wave * 32 + 16 + m) * KP + k0 + koff];
        acc00 = __builtin_amdgcn_mfma_f32_16x16x32_bf16(A0, B0, acc00, 0, 0, 0);
        acc01 = __builtin_amdgcn_mfma_f32_16x16x32_bf16(A0, B1, acc01, 0, 0, 0);
        acc10 = __builtin_amdgcn_mfma_f32_16x16x32_bf16(A1, B0, acc10, 0, 0, 0);
        acc11 = __builtin_amdgcn_mfma_f32_16x16x32_bf16(A1, B1, acc11, 0, 0, 0);
    }
    int col0 = wave * 32 + m;
    int col1 = wave * 32 + 16 + m;
#pragma unroll
    for (int reg = 0; reg < 4; reg++) {
        int r0 = row0 + half * 4 + reg;
        int r1 = r0 + 16;
        float v00 = acc00[reg], v01 = acc01[reg];
        float v10 = acc10[reg], v11 = acc11[reg];
        if (r0 < N_NODES) {
            if (col0 < 64) p[(size_t)r0 * 64 + col0] = (unsigned short)f2bf(v00);
            else           out[(size_t)r0 * 64 + col0 - 64] = v00 + b2[col0 - 64];
            if (col1 < 64) p[(size_t)r0 * 64 + col1] = (unsigned short)f2bf(v01);
            else           out[(size_t)r0 * 64 + col1 - 64] = v01 + b2[col1 - 64];
        }
        if (r1 < N_NODES) {
            if (col0 < 64) p[(size_t)r1 * 64 + col0] = (unsigned short)f2bf(v10);
            else           out[(size_t)r1 * 64 + col0 - 64] = v10 + b2[col0 - 64];
            if (col1 < 64) p[(size_t)r1 * 64 + col1] = (unsigned short)f2bf(v11);
            else           out[(size_t)r1 * 64 + col1 - 64] = v11 + b2[col1 - 64];
        }
    }
}

// ---------------------------------------------------------------------------
// Gather 2 + finalize: out[n] += (sum_{j in N(n)} p[j]) / deg(n)
// thread = (node, 16B chunk c in 0..7); manual 2-edge unroll.
// ---------------------------------------------------------------------------
__global__ __launch_bounds__(256) void gather2_kernel(
    const int* __restrict__ rowstart, const int* __restrict__ cnt,
    const int* __restrict__ adj, const uint4* __restrict__ p4,
    float* __restrict__ out)
{
    int idx = blockIdx.x * 256 + threadIdx.x;
    if (idx >= N_NODES * 8) return;
    int node = idx >> 3;
    int c = idx & 7;
    int beg = rowstart[node];
    int d = cnt[node];
    int end = beg + d;
    float a0=0,a1=0,a2=0,a3=0,a4=0,a5=0,a6=0,a7=0;
    float b0=0,b1=0,b2=0,b3=0,b4=0,b5=0,b6=0,b7=0;
    int j = beg;
    for (; j + 1 < end; j += 2) {
        int s0 = adj[j];
        int s1 = adj[j + 1];
        uint4 u = p4[(size_t)s0 * 8 + c];
        uint4 v = p4[(size_t)s1 * 8 + c];
        a0 += blo(u.x); a1 += bhi(u.x); a2 += blo(u.y); a3 += bhi(u.y);
        a4 += blo(u.z); a5 += bhi(u.z); a6 += blo(u.w); a7 += bhi(u.w);
        b0 += blo(v.x); b1 += bhi(v.x); b2 += blo(v.y); b3 += bhi(v.y);
        b4 += blo(v.z); b5 += bhi(v.z); b6 += blo(v.w); b7 += bhi(v.w);
    }
    if (j < end) {
        int s0 = adj[j];
        uint4 u = p4[(size_t)s0 * 8 + c];
        a0 += blo(u.x); a1 += bhi(u.x); a2 += blo(u.y); a3 += bhi(u.y);
        a4 += blo(u.z); a5 += bhi(u.z); a6 += blo(u.w); a7 += bhi(u.w);
    }
    a0 += b0; a1 += b1; a2 += b2; a3 += b3;
    a4 += b4; a5 += b5; a6 += b6; a7 += b7;
    float id = 1.0f / (float)max(d, 1);
    float4* o4 = (float4*)out;
    size_t base = (size_t)node * 16 + 2 * c;
    float4 u = o4[base], v = o4[base + 1];
    u.x = fmaf(a0, id, u.x); u.y = fmaf(a1, id, u.y);
    u.z = fmaf(a2, id, u.z); u.w = fmaf(a3, id, u.w);
    v.x = fmaf(a4, id, v.x); v.y = fmaf(a5, id, v.y);
    v.z = fmaf(a6, id, v.z); v.w = fmaf(a7, id, v.w);
    o4[base] = u; o4[base + 1] = v;
}

extern "C" void kernel_launch(void* const* d_in, const int* in_sizes, int n_in,
                              void* d_out, int out_size, void* d_ws, size_t ws_size,
                              hipStream_t stream)
{
    const float* x   = (const float*)d_in[0];
    const int*   ei  = (const int*)d_in[1];
    const float* w1l = (const float*)d_in[2];
    const float* w1r = (const float*)d_in[3];
    const float* b1  = (const float*)d_in[4];
    const float* w2l = (const float*)d_in[5];
    const float* w2r = (const float*)d_in[6];
    const float* b2  = (const float*)d_in[7];
    float* out = (float*)d_out;

    int E = in_sizes[1] / 2;                  // edge_index is [2, E]
    const int* src = ei;
    const int* dst = ei + E;

    // Workspace layout (4B units, arrays kept 16B-aligned).
    int* gh       = (int*)d_ws;                        // 39200
    int* ofs      = gh + NWG * NB;                     // 39200
    int* base     = ofs + NWG * NB;                    // 256
    int* cnt      = base + 256;                        // 50000
    int* rowstart = cnt + N_NODES;                     // 50000
    uint2* pairs  = (uint2*)(rowstart + N_NODES);      // 800000 uint2
    int* adj      = (int*)(pairs + 800000);            // 800000
    unsigned short* xb  = (unsigned short*)(adj + 800000); // 50000*96 bf16
    unsigned short* agg = xb + (size_t)N_NODES * IN_C; // 50016*96 (xb OOB pad lands here)
    unsigned short* h   = agg + (size_t)MROWS * 96;    // 50016*128 bf16
    unsigned short* p   = h  + (size_t)MROWS * 128;    // 50000*64 bf16
    unsigned short* Wt1 = p  + (size_t)N_NODES * 64;   // 128*192 bf16
    unsigned short* Wt2 = Wt1 + 128 * 192;             // 128*128 bf16

    // CSR build (locality-aware two-pass counting sort; no memset needed)
    parta_hist<<<NWG, 256, 0, stream>>>(dst, gh, E);
    parta_scan<<<1, 256, 0, stream>>>(gh, ofs, base);
    parta_scatter<<<NWG, 256, 0, stream>>>(src, dst, ofs, pairs, E);
    partb_csr<<<NB, 256, 0, stream>>>(pairs, base, rowstart, cnt, adj);

    conv_x_kernel<<<(N_NODES * 12 + 255) / 256, 256, 0, stream>>>(
        x, (uint4*)xb);
    conv_w_kernel<<<(128 * 192 + 128 * 128 + 255) / 256, 256, 0, stream>>>(
        w1l, w1r, w2l, w2r, Wt1, Wt2);

    gather1_kernel<<<(N_NODES * 12 + 255) / 256, 256, 0, stream>>>(
        rowstart, cnt, adj, (const uint4*)xb, (uint4*)agg);

    gemm1_mfma<<<MROWS / 32, 256, 0, stream>>>(
        (const uint4*)agg, (const uint4*)xb, (const uint4*)Wt1, b1, h);
    gemm2_mfma<<<MROWS / 32, 256, 0, stream>>>(
        (const uint4*)h, (const uint4*)Wt2, b2, p, out);

    gather2_kernel<<<(N_NODES * 8 + 255) / 256, 256, 0, stream>>>(
        rowstart, cnt, adj, (const uint4*)p, out);
}

// Round 9
// 203.168 us; speedup vs baseline: 4.8030x; 1.0254x over previous
//
#include <hip/hip_runtime.h>
#include <hip/hip_bf16.h>

#define N_NODES 50000
#define IN_C    96
#define HID_C   128
#define OUT_C   64
#define MROWS   50016 // 32-row-tile padded M

// CSR-build partition params (R4-proven)
#define NB      200   // coarse buckets
#define BSZ     250   // nodes per bucket (200*250 = 50000)
#define WCHUNK  4096  // edges per workgroup in partition passes
#define NWG     196   // ceil(800000/4096)

// conv fusion split
#define XBLKS   2344  // ceil(50000*12/256)
#define WBLKS   160   // (128*192 + 128*128)/256

typedef __attribute__((ext_vector_type(8))) short short8;  // 8 bf16 (4 VGPR)
typedef __attribute__((ext_vector_type(4))) float f32x4;

// round-to-nearest-even fp32 -> bf16 bits
__device__ inline unsigned int f2bf(float f) {
    unsigned int u = __float_as_uint(f);
    return (u + 0x7fffu + ((u >> 16) & 1u)) >> 16;
}
__device__ inline unsigned int pack2(float lo, float hi) {
    return f2bf(lo) | (f2bf(hi) << 16);
}
__device__ inline float blo(unsigned int u) { return __uint_as_float(u << 16); }
__device__ inline float bhi(unsigned int u) { return __uint_as_float(u & 0xffff0000u); }

// ---------------------------------------------------------------------------
// P1: per-WG coarse histogram (LDS, no global atomics).
// ---------------------------------------------------------------------------
__global__ __launch_bounds__(256) void parta_hist(
    const int* __restrict__ dst, int* __restrict__ gh, int E)
{
    __shared__ int h[NB];
    int t = threadIdx.x;
    if (t < NB) h[t] = 0;
    __syncthreads();
    int base_e = blockIdx.x * WCHUNK;
    for (int i = t; i < WCHUNK; i += 256) {
        int e = base_e + i;
        if (e < E) atomicAdd(&h[dst[e] / BSZ], 1);
    }
    __syncthreads();
    if (t < NB) gh[blockIdx.x * NB + t] = h[t];
}

// ---------------------------------------------------------------------------
// P2: bucket bases (exclusive scan of totals) + per-(WG,bucket) offsets.
// ---------------------------------------------------------------------------
__global__ __launch_bounds__(256) void parta_scan(
    const int* __restrict__ gh, int* __restrict__ ofs,
    int* __restrict__ base)
{
    __shared__ int buf[256];
    int t = threadIdx.x;
    int tot = 0;
    if (t < NB) {
        for (int w = 0; w < NWG; w++) tot += gh[w * NB + t];
    }
    buf[t] = tot;
    __syncthreads();
    for (int off = 1; off < 256; off <<= 1) {       // inclusive scan
        int v = (t >= off) ? buf[t - off] : 0;
        __syncthreads();
        buf[t] += v;
        __syncthreads();
    }
    if (t < NB) {
        int excl = buf[t] - tot;
        base[t] = excl;
        if (t == NB - 1) base[NB] = excl + tot;     // == E
        int run = excl;
        for (int w = 0; w < NWG; w++) {
            ofs[w * NB + t] = run;
            run += gh[w * NB + t];
        }
    }
}

// ---------------------------------------------------------------------------
// P3: partition edges into bucket-ordered (src,dst) pairs; each WG's writes
// per bucket form a contiguous run (fully-dirty lines, no writeback ampl.).
// ---------------------------------------------------------------------------
__global__ __launch_bounds__(256) void parta_scatter(
    const int* __restrict__ src, const int* __restrict__ dst,
    const int* __restrict__ ofs, uint2* __restrict__ pairs, int E)
{
    __shared__ int cur[NB];
    int t = threadIdx.x;
    if (t < NB) cur[t] = ofs[blockIdx.x * NB + t];
    __syncthreads();
    int base_e = blockIdx.x * WCHUNK;
    for (int i = t; i < WCHUNK; i += 256) {
        int e = base_e + i;
        if (e < E) {
            int d = dst[e];
            int pos = atomicAdd(&cur[d / BSZ], 1);
            pairs[pos] = make_uint2((unsigned)src[e], (unsigned)d);
        }
    }
}

// ---------------------------------------------------------------------------
// P4: per-bucket fine CSR: LDS 250-bin histogram + scan + rank; writes
// rowstart/cnt and a contiguous adj region per bucket.
// ---------------------------------------------------------------------------
__global__ __launch_bounds__(256) void partb_csr(
    const uint2* __restrict__ pairs, const int* __restrict__ base,
    int* __restrict__ rowstart, int* __restrict__ cnt,
    int* __restrict__ adj)
{
    __shared__ int h[256];
    __shared__ int buf[256];
    __shared__ int cur[256];
    int b = blockIdx.x;
    int t = threadIdx.x;
    int beg = base[b], end = base[b + 1];
    int node0 = b * BSZ;
    h[t] = 0;
    __syncthreads();
    for (int i = beg + t; i < end; i += 256)
        atomicAdd(&h[(int)pairs[i].y - node0], 1);
    __syncthreads();
    int c = h[t];
    buf[t] = c;
    __syncthreads();
    for (int off = 1; off < 256; off <<= 1) {       // inclusive scan
        int v = (t >= off) ? buf[t - off] : 0;
        __syncthreads();
        buf[t] += v;
        __syncthreads();
    }
    int excl = buf[t] - c;
    if (t < BSZ) {
        rowstart[node0 + t] = beg + excl;
        cnt[node0 + t] = c;
    }
    cur[t] = beg + excl;
    __syncthreads();
    for (int i = beg + t; i < end; i += 256) {
        uint2 pr = pairs[i];
        int pos = atomicAdd(&cur[(int)pr.y - node0], 1);
        adj[pos] = (int)pr.x;
    }
}

// ---------------------------------------------------------------------------
// Fused converter: blocks [0,XBLKS) convert x fp32 -> xb bf16 [50000][96];
// blocks [XBLKS, XBLKS+WBLKS) build W1t[128][192] / W2t[128][128].
// ---------------------------------------------------------------------------
__global__ __launch_bounds__(256) void conv_all_kernel(
    const float* __restrict__ x, uint4* __restrict__ xb4,
    const float* __restrict__ w1l, const float* __restrict__ w1r,
    const float* __restrict__ w2l, const float* __restrict__ w2r,
    unsigned short* __restrict__ wt1, unsigned short* __restrict__ wt2)
{
    int blk = blockIdx.x;
    if (blk < XBLKS) {
        int idx = blk * 256 + threadIdx.x;
        if (idx >= N_NODES * 12) return;
        const float4* x4 = (const float4*)x;
        float4 u = x4[(size_t)idx * 2];
        float4 v = x4[(size_t)idx * 2 + 1];
        uint4 w;
        w.x = pack2(u.x, u.y); w.y = pack2(u.z, u.w);
        w.z = pack2(v.x, v.y); w.w = pack2(v.z, v.w);
        xb4[idx] = w;
    } else {
        int i = (blk - XBLKS) * 256 + threadIdx.x;
        if (i < 128 * 192) {
            int col = i / 192, k = i - col * 192;
            float v = (k < 96) ? w1l[k * 128 + col] : w1r[(k - 96) * 128 + col];
            wt1[i] = (unsigned short)f2bf(v);
        } else {
            int j = i - 128 * 192;
            int col = j / 128, k = j - col * 128;
            float v = (col < 64) ? w2l[k * 64 + col] : w2r[k * 64 + col - 64];
            wt2[j] = (unsigned short)f2bf(v);
        }
    }
}

// ---------------------------------------------------------------------------
// Gather 1: agg[n] = (sum_{j in N(n)} xb[j]) / deg(n), bf16 out [50000][96].
// thread = (node, 16B chunk c in 0..11); 4-edge unroll -> 4 loads in flight.
// ---------------------------------------------------------------------------
__global__ __launch_bounds__(256) void gather1_kernel(
    const int* __restrict__ rowstart, const int* __restrict__ cnt,
    const int* __restrict__ adj, const uint4* __restrict__ xb4,
    uint4* __restrict__ agg4)
{
    int idx = blockIdx.x * 256 + threadIdx.x;
    if (idx >= N_NODES * 12) return;
    int node = idx / 12;
    int c = idx - node * 12;
    int beg = rowstart[node];
    int d = cnt[node];
    int end = beg + d;
    float a0=0,a1=0,a2=0,a3=0,a4=0,a5=0,a6=0,a7=0;
    float b0=0,b1=0,b2=0,b3=0,b4=0,b5=0,b6=0,b7=0;
    int j = beg;
    for (; j + 3 < end; j += 4) {
        int s0 = adj[j];
        int s1 = adj[j + 1];
        int s2 = adj[j + 2];
        int s3 = adj[j + 3];
        uint4 u = xb4[(size_t)s0 * 12 + c];
        uint4 v = xb4[(size_t)s1 * 12 + c];
        uint4 w = xb4[(size_t)s2 * 12 + c];
        uint4 z = xb4[(size_t)s3 * 12 + c];
        a0 += blo(u.x); a1 += bhi(u.x); a2 += blo(u.y); a3 += bhi(u.y);
        a4 += blo(u.z); a5 += bhi(u.z); a6 += blo(u.w); a7 += bhi(u.w);
        b0 += blo(v.x); b1 += bhi(v.x); b2 += blo(v.y); b3 += bhi(v.y);
        b4 += blo(v.z); b5 += bhi(v.z); b6 += blo(v.w); b7 += bhi(v.w);
        a0 += blo(w.x); a1 += bhi(w.x); a2 += blo(w.y); a3 += bhi(w.y);
        a4 += blo(w.z); a5 += bhi(w.z); a6 += blo(w.w); a7 += bhi(w.w);
        b0 += blo(z.x); b1 += bhi(z.x); b2 += blo(z.y); b3 += bhi(z.y);
        b4 += blo(z.z); b5 += bhi(z.z); b6 += blo(z.w); b7 += bhi(z.w);
    }
    for (; j < end; j++) {
        int s0 = adj[j];
        uint4 u = xb4[(size_t)s0 * 12 + c];
        a0 += blo(u.x); a1 += bhi(u.x); a2 += blo(u.y); a3 += bhi(u.y);
        a4 += blo(u.z); a5 += bhi(u.z); a6 += blo(u.w); a7 += bhi(u.w);
    }
    a0 += b0; a1 += b1; a2 += b2; a3 += b3;
    a4 += b4; a5 += b5; a6 += b6; a7 += b7;
    float id = 1.0f / (float)max(d, 1);
    uint4 w;
    w.x = pack2(a0 * id, a1 * id); w.y = pack2(a2 * id, a3 * id);
    w.z = pack2(a4 * id, a5 * id); w.w = pack2(a6 * id, a7 * id);
    agg4[(size_t)node * 12 + c] = w;
}

// ---------------------------------------------------------------------------
// GEMM1 (bf16 MFMA): h = relu([agg|x] @ W1t^T + b1)  [50000 x 128], h bf16.
// A-tile k-cols 0..95 from agg, 96..191 from xb. Non-persistent (R4-proven).
// ---------------------------------------------------------------------------
__global__ __launch_bounds__(256) void gemm1_mfma(
    const uint4* __restrict__ agg4, const uint4* __restrict__ xb4,
    const uint4* __restrict__ w4,
    const float* __restrict__ b1, unsigned short* __restrict__ h)
{
    constexpr int KD = 192, KP = KD + 8;          // padded bf16 stride (200)
    __shared__ unsigned short lw[128 * KP];       // 51200 B
    __shared__ unsigned short la[32 * KP];        // 12800 B
    int t = threadIdx.x;
    uint4* lw4 = (uint4*)lw;
    uint4* la4 = (uint4*)la;
    for (int i = t; i < 128 * 24; i += 256) {
        int r = i / 24, c = i - r * 24;
        lw4[r * 25 + c] = w4[i];
    }
    int row0 = blockIdx.x * 32;
    for (int i = t; i < 32 * 24; i += 256) {
        int r = i / 24, c = i - r * 24;
        // rows >= N_NODES: xb reads run into agg region (valid mem, discarded)
        la4[r * 25 + c] = (c < 12)
            ? agg4[(size_t)(row0 + r) * 12 + c]
            : xb4[(size_t)(row0 + r) * 12 + (c - 12)];
    }
    __syncthreads();

    int wave = t >> 6, lane = t & 63;
    int m = lane & 15, half = lane >> 4;          // 0..3
    int koff = half * 8;
    f32x4 acc00 = {}, acc01 = {}, acc10 = {}, acc11 = {};
#pragma unroll
    for (int k0 = 0; k0 < KD; k0 += 32) {
        short8 A0 = *(const short8*)&la[(m)      * KP + k0 + koff];
        short8 A1 = *(const short8*)&la[(16 + m) * KP + k0 + koff];
        short8 B0 = *(const short8*)&lw[(wave * 32 + m)      * KP + k0 + koff];
        short8 B1 = *(const short8*)&lw[(wave * 32 + 16 + m) * KP + k0 + koff];
        acc00 = __builtin_amdgcn_mfma_f32_16x16x32_bf16(A0, B0, acc00, 0, 0, 0);
        acc01 = __builtin_amdgcn_mfma_f32_16x16x32_bf16(A0, B1, acc01, 0, 0, 0);
        acc10 = __builtin_amdgcn_mfma_f32_16x16x32_bf16(A1, B0, acc10, 0, 0, 0);
        acc11 = __builtin_amdgcn_mfma_f32_16x16x32_bf16(A1, B1, acc11, 0, 0, 0);
    }
    int col0 = wave * 32 + m;
    int col1 = wave * 32 + 16 + m;
    float bias0 = b1[col0], bias1 = b1[col1];
#pragma unroll
    for (int reg = 0; reg < 4; reg++) {
        int r0 = row0 + half * 4 + reg;
        int r1 = r0 + 16;
        if (r0 < N_NODES) {
            h[(size_t)r0 * 128 + col0] = (unsigned short)f2bf(fmaxf(acc00[reg] + bias0, 0.f));
            h[(size_t)r0 * 128 + col1] = (unsigned short)f2bf(fmaxf(acc01[reg] + bias1, 0.f));
        }
        if (r1 < N_NODES) {
            h[(size_t)r1 * 128 + col0] = (unsigned short)f2bf(fmaxf(acc10[reg] + bias0, 0.f));
            h[(size_t)r1 * 128 + col1] = (unsigned short)f2bf(fmaxf(acc11[reg] + bias1, 0.f));
        }
    }
}

// ---------------------------------------------------------------------------
// GEMM2 (bf16 MFMA): [p|q] = h @ W2t^T; p bf16 (cols 0..63),
// q = +b2 -> out fp32 (cols 64..127). Non-persistent (R4-proven).
// ---------------------------------------------------------------------------
__global__ __launch_bounds__(256) void gemm2_mfma(
    const uint4* __restrict__ h4, const uint4* __restrict__ w4,
    const float* __restrict__ b2, unsigned short* __restrict__ p,
    float* __restrict__ out)
{
    constexpr int KD = 128, KP = KD + 8;          // 136
    __shared__ unsigned short lw[128 * KP];       // 34816 B
    __shared__ unsigned short la[32 * KP];        // 8704 B
    int t = threadIdx.x;
    uint4* lw4 = (uint4*)lw;
    uint4* la4 = (uint4*)la;
    for (int i = t; i < 128 * 16; i += 256) {
        int r = i >> 4, c = i & 15;
        lw4[r * 17 + c] = w4[i];
    }
    int row0 = blockIdx.x * 32;
    for (int i = t; i < 32 * 16; i += 256) {
        int r = i >> 4, c = i & 15;
        la4[r * 17 + c] = h4[(size_t)(row0 + r) * 16 + c];
    }
    __syncthreads();

    int wave = t >> 6, lane = t & 63;
    int m = lane & 15, half = lane >> 4;
    int koff = half * 8;
    f32x4 acc00 = {}, acc01 = {}, acc10 = {}, acc11 = {};
#pragma unroll
    for (int k0 = 0; k0 < KD; k0 += 32) {
        short8 A0 = *(const short8*)&la[(m)      * KP + k0 + koff];
        short8 A1 = *(const short8*)&la[(16 + m) * KP + k0 + koff];
        short8 B0 = *(const short8*)&lw[(wave * 32 + m)      * KP + k0 + koff];
        short8 B1 = *(const short8*)&lw[(wave * 32 + 16 + m) * KP + k0 + koff];
        acc00 = __builtin_amdgcn_mfma_f32_16x16x32_bf16(A0, B0, acc00, 0, 0, 0);
        acc01 = __builtin_amdgcn_mfma_f32_16x16x32_bf16(A0, B1, acc01, 0, 0, 0);
        acc10 = __builtin_amdgcn_mfma_f32_16x16x32_bf16(A1, B0, acc10, 0, 0, 0);
        acc11 = __builtin_amdgcn_mfma_f32_16x16x32_bf16(A1, B1, acc11, 0, 0, 0);
    }
    int col0 = wave * 32 + m;
    int col1 = wave * 32 + 16 + m;
#pragma unroll
    for (int reg = 0; reg < 4; reg++) {
        int r0 = row0 + half * 4 + reg;
        int r1 = r0 + 16;
        float v00 = acc00[reg], v01 = acc01[reg];
        float v10 = acc10[reg], v11 = acc11[reg];
        if (r0 < N_NODES) {
            if (col0 < 64) p[(size_t)r0 * 64 + col0] = (unsigned short)f2bf(v00);
            else           out[(size_t)r0 * 64 + col0 - 64] = v00 + b2[col0 - 64];
            if (col1 < 64) p[(size_t)r0 * 64 + col1] = (unsigned short)f2bf(v01);
            else           out[(size_t)r0 * 64 + col1 - 64] = v01 + b2[col1 - 64];
        }
        if (r1 < N_NODES) {
            if (col0 < 64) p[(size_t)r1 * 64 + col0] = (unsigned short)f2bf(v10);
            else           out[(size_t)r1 * 64 + col0 - 64] = v10 + b2[col0 - 64];
            if (col1 < 64) p[(size_t)r1 * 64 + col1] = (unsigned short)f2bf(v11);
            else           out[(size_t)r1 * 64 + col1 - 64] = v11 + b2[col1 - 64];
        }
    }
}

// ---------------------------------------------------------------------------
// Gather 2 + finalize: out[n] += (sum_{j in N(n)} p[j]) / deg(n)
// thread = (node, 16B chunk c in 0..7); 4-edge unroll.
// ---------------------------------------------------------------------------
__global__ __launch_bounds__(256) void gather2_kernel(
    const int* __restrict__ rowstart, const int* __restrict__ cnt,
    const int* __restrict__ adj, const uint4* __restrict__ p4,
    float* __restrict__ out)
{
    int idx = blockIdx.x * 256 + threadIdx.x;
    if (idx >= N_NODES * 8) return;
    int node = idx >> 3;
    int c = idx & 7;
    int beg = rowstart[node];
    int d = cnt[node];
    int end = beg + d;
    float a0=0,a1=0,a2=0,a3=0,a4=0,a5=0,a6=0,a7=0;
    float b0=0,b1=0,b2=0,b3=0,b4=0,b5=0,b6=0,b7=0;
    int j = beg;
    for (; j + 3 < end; j += 4) {
        int s0 = adj[j];
        int s1 = adj[j + 1];
        int s2 = adj[j + 2];
        int s3 = adj[j + 3];
        uint4 u = p4[(size_t)s0 * 8 + c];
        uint4 v = p4[(size_t)s1 * 8 + c];
        uint4 w = p4[(size_t)s2 * 8 + c];
        uint4 z = p4[(size_t)s3 * 8 + c];
        a0 += blo(u.x); a1 += bhi(u.x); a2 += blo(u.y); a3 += bhi(u.y);
        a4 += blo(u.z); a5 += bhi(u.z); a6 += blo(u.w); a7 += bhi(u.w);
        b0 += blo(v.x); b1 += bhi(v.x); b2 += blo(v.y); b3 += bhi(v.y);
        b4 += blo(v.z); b5 += bhi(v.z); b6 += blo(v.w); b7 += bhi(v.w);
        a0 += blo(w.x); a1 += bhi(w.x); a2 += blo(w.y); a3 += bhi(w.y);
        a4 += blo(w.z); a5 += bhi(w.z); a6 += blo(w.w); a7 += bhi(w.w);
        b0 += blo(z.x); b1 += bhi(z.x); b2 += blo(z.y); b3 += bhi(z.y);
        b4 += blo(z.z); b5 += bhi(z.z); b6 += blo(z.w); b7 += bhi(z.w);
    }
    for (; j < end; j++) {
        int s0 = adj[j];
        uint4 u = p4[(size_t)s0 * 8 + c];
        a0 += blo(u.x); a1 += bhi(u.x); a2 += blo(u.y); a3 += bhi(u.y);
        a4 += blo(u.z); a5 += bhi(u.z); a6 += blo(u.w); a7 += bhi(u.w);
    }
    a0 += b0; a1 += b1; a2 += b2; a3 += b3;
    a4 += b4; a5 += b5; a6 += b6; a7 += b7;
    float id = 1.0f / (float)max(d, 1);
    float4* o4 = (float4*)out;
    size_t base = (size_t)node * 16 + 2 * c;
    float4 u = o4[base], v = o4[base + 1];
    u.x = fmaf(a0, id, u.x); u.y = fmaf(a1, id, u.y);
    u.z = fmaf(a2, id, u.z); u.w = fmaf(a3, id, u.w);
    v.x = fmaf(a4, id, v.x); v.y = fmaf(a5, id, v.y);
    v.z = fmaf(a6, id, v.z); v.w = fmaf(a7, id, v.w);
    o4[base] = u; o4[base + 1] = v;
}

extern "C" void kernel_launch(void* const* d_in, const int* in_sizes, int n_in,
                              void* d_out, int out_size, void* d_ws, size_t ws_size,
                              hipStream_t stream)
{
    const float* x   = (const float*)d_in[0];
    const int*   ei  = (const int*)d_in[1];
    const float* w1l = (const float*)d_in[2];
    const float* w1r = (const float*)d_in[3];
    const float* b1  = (const float*)d_in[4];
    const float* w2l = (const float*)d_in[5];
    const float* w2r = (const float*)d_in[6];
    const float* b2  = (const float*)d_in[7];
    float* out = (float*)d_out;

    int E = in_sizes[1] / 2;                  // edge_index is [2, E]
    const int* src = ei;
    const int* dst = ei + E;

    // Workspace layout (4B units, arrays kept 16B-aligned).
    int* gh       = (int*)d_ws;                        // 39200
    int* ofs      = gh + NWG * NB;                     // 39200
    int* base     = ofs + NWG * NB;                    // 256
    int* cnt      = base + 256;                        // 50000
    int* rowstart = cnt + N_NODES;                     // 50000
    uint2* pairs  = (uint2*)(rowstart + N_NODES);      // 800000 uint2
    int* adj      = (int*)(pairs + 800000);            // 800000
    unsigned short* xb  = (unsigned short*)(adj + 800000); // 50000*96 bf16
    unsigned short* agg = xb + (size_t)N_NODES * IN_C; // 50016*96 (xb OOB pad lands here)
    unsigned short* h   = agg + (size_t)MROWS * 96;    // 50016*128 bf16
    unsigned short* p   = h  + (size_t)MROWS * 128;    // 50000*64 bf16
    unsigned short* Wt1 = p  + (size_t)N_NODES * 64;   // 128*192 bf16
    unsigned short* Wt2 = Wt1 + 128 * 192;             // 128*128 bf16

    // CSR build (locality-aware two-pass counting sort; no memset needed)
    parta_hist<<<NWG, 256, 0, stream>>>(dst, gh, E);
    parta_scan<<<1, 256, 0, stream>>>(gh, ofs, base);
    parta_scatter<<<NWG, 256, 0, stream>>>(src, dst, ofs, pairs, E);
    partb_csr<<<NB, 256, 0, stream>>>(pairs, base, rowstart, cnt, adj);

    conv_all_kernel<<<XBLKS + WBLKS, 256, 0, stream>>>(
        x, (uint4*)xb, w1l, w1r, w2l, w2r, Wt1, Wt2);

    gather1_kernel<<<(N_NODES * 12 + 255) / 256, 256, 0, stream>>>(
        rowstart, cnt, adj, (const uint4*)xb, (uint4*)agg);

    gemm1_mfma<<<MROWS / 32, 256, 0, stream>>>(
        (const uint4*)agg, (const uint4*)xb, (const uint4*)Wt1, b1, h);
    gemm2_mfma<<<MROWS / 32, 256, 0, stream>>>(
        (const uint4*)h, (const uint4*)Wt2, b2, p, out);

    gather2_kernel<<<(N_NODES * 8 + 255) / 256, 256, 0, stream>>>(
        rowstart, cnt, adj, (const uint4*)p, out);
}